// Round 2
// baseline (440.917 us; speedup 1.0000x reference)
//
#include <hip/hip_runtime.h>
#include <hip/hip_bf16.h>
#include <cstddef>

#define EE 1024            // E
#define MTOT 8192          // B*E

using floatx4 = __attribute__((ext_vector_type(4))) float;
using bf16x8  = __attribute__((ext_vector_type(8))) __bf16;

union FragU { uint4 u; bf16x8 b; };

__device__ __forceinline__ float elu1(float x) {
    return x > 0.f ? x + 1.f : __expf(x);
}

__device__ __forceinline__ unsigned int pack2bf(float x, float y) {
    __hip_bfloat162 h = __float22bfloat162_rn(make_float2(x, y));
    union { __hip_bfloat162 h; unsigned int u; } c;
    c.h = h;
    return c.u;
}

__device__ __forceinline__ uint4 pack8bf(const float4 a, const float4 b) {
    uint4 r;
    r.x = pack2bf(a.x, a.y); r.y = pack2bf(a.z, a.w);
    r.z = pack2bf(b.x, b.y); r.w = pack2bf(b.z, b.w);
    return r;
}

__device__ __forceinline__ unsigned short f2bf(float x) {
    union { __hip_bfloat16 h; unsigned short s; } c;
    c.h = __float2bfloat16(x);
    return c.s;
}

__device__ __forceinline__ void unp8(const uint4 p, float4& a, float4& b) {
    a.x = __uint_as_float(p.x << 16); a.y = __uint_as_float(p.x & 0xffff0000u);
    a.z = __uint_as_float(p.y << 16); a.w = __uint_as_float(p.y & 0xffff0000u);
    b.x = __uint_as_float(p.z << 16); b.y = __uint_as_float(p.z & 0xffff0000u);
    b.z = __uint_as_float(p.w << 16); b.w = __uint_as_float(p.w & 0xffff0000u);
}

__device__ __forceinline__ void ld_lds16(const unsigned short* g, unsigned short* l) {
    __builtin_amdgcn_global_load_lds(
        (const __attribute__((address_space(1))) void*)g,
        (__attribute__((address_space(3))) void*)l, 16, 0, 0);
}

// fp32 -> bf16 bulk convert, 8 elems/thread
__global__ __launch_bounds__(256)
void cvt_bf16(const float* __restrict__ src, unsigned short* __restrict__ dst, int n8) {
    const int i = blockIdx.x * 256 + threadIdx.x;
    if (i >= n8) return;
    const float4 a = ((const float4*)src)[2 * i];
    const float4 b = ((const float4*)src)[2 * i + 1];
    ((uint4*)dst)[i] = pack8bf(a, b);
}

// All four weight matrices in one launch. Regions (uint4-chunk counts):
// Wq 262144 | Wk 262144 | Wv 262144 | Wo 131072 -> 917504 chunks total.
__global__ __launch_bounds__(256)
void cvt_w(const float* __restrict__ Wq, const float* __restrict__ Wk,
           const float* __restrict__ Wv, const float* __restrict__ Wo,
           unsigned short* __restrict__ wb, unsigned short* __restrict__ wob) {
    const int i = blockIdx.x * 256 + threadIdx.x;
    if (i >= 917504) return;
    const float* src;
    unsigned short* dst;
    int off;
    if (i < 262144)      { src = Wq; dst = wb;           off = i; }
    else if (i < 524288) { src = Wk; dst = wb + 2097152; off = i - 262144; }
    else if (i < 786432) { src = Wv; dst = wb + 4194304; off = i - 524288; }
    else                 { src = Wo; dst = wob;          off = i - 786432; }
    const float4 a = ((const float4*)src)[2 * off];
    const float4 b = ((const float4*)src)[2 * off + 1];
    ((uint4*)dst)[off] = pack8bf(a, b);
}

// ---- m97-style MFMA core (kept for gemm_out): bf16 A[M][K] x B[N][K]^T,
// 128x128 tile, BK=32, global_load_lds width-16 staging.
template<int K>
__device__ __forceinline__ void mfma_core(const unsigned short* __restrict__ A,
                                          const unsigned short* __restrict__ B,
                                          int m0, int n0,
                                          unsigned short* As, unsigned short* Bs,
                                          floatx4 (&acc)[4][4]) {
    const int t = threadIdx.x;
    const int w = t >> 6, l = t & 63;
    const int wm = (w >> 1) * 64, wn = (w & 1) * 64;
    const int lm = l & 15, lq = l >> 4;
    const int ar = l >> 2;
    const int ac = (l & 3) * 8;
    const unsigned short* Ag0 = A + (size_t)(m0 + 32 * w + ar) * K + ac;
    const unsigned short* Ag1 = Ag0 + (size_t)16 * K;
    const unsigned short* Bg0 = B + (size_t)(n0 + 32 * w + ar) * K + ac;
    const unsigned short* Bg1 = Bg0 + (size_t)16 * K;
    unsigned short* Al0 = As + 1024 * w;
    unsigned short* Al1 = As + 1024 * w + 512;
    unsigned short* Bl0 = Bs + 1024 * w;
    unsigned short* Bl1 = Bs + 1024 * w + 512;

    for (int kb = 0; kb < K; kb += 32) {
        __syncthreads();
        ld_lds16(Ag0 + kb, Al0);
        ld_lds16(Ag1 + kb, Al1);
        ld_lds16(Bg0 + kb, Bl0);
        ld_lds16(Bg1 + kb, Bl1);
        __syncthreads();
        FragU af[4], bf[4];
        #pragma unroll
        for (int i = 0; i < 4; ++i)
            af[i].u = *(const uint4*)&As[(wm + i * 16 + lm) * 32 + lq * 8];
        #pragma unroll
        for (int j = 0; j < 4; ++j)
            bf[j].u = *(const uint4*)&Bs[(wn + j * 16 + lm) * 32 + lq * 8];
        #pragma unroll
        for (int i = 0; i < 4; ++i)
            #pragma unroll
            for (int j = 0; j < 4; ++j)
                acc[i][j] = __builtin_amdgcn_mfma_f32_16x16x32_bf16(
                    af[i].b, bf[j].b, acc[i][j], 0, 0, 0);
    }
}

// ============================================================================
// 256x256 8-phase counted-vmcnt GEMM for the QKV projection.
// A = xb [8192][2048] bf16, B = wb [3072][2048] (Wq|Wk|Wv rows, B^T layout).
// 8 waves (2M x 4N), per-wave 128x64 output, BK=64, double-buffered 128KiB LDS.
//
// LDS layout (per 256x64 tile region, 32 KiB): 16 row-groups of 16 rows.
// Group g stored as 8 col-blocks x 16 rows x 16B chunks:
//   ushort off = g*1024 + cb*128 + r*8      (cb = col/8, r = row%16)
// Written linearly by global_load_lds (1024B per instr = one kh-half of a
// group) with the PERMUTATION applied on the per-lane GLOBAL address
// (rule #21: linear LDS dest + pre-permuted source). Fragment ds_read_b128
// then hits bytes quad*256 + lm*16 -> 64 lanes perfectly contiguous over
// 1024B -> zero bank conflicts by construction.
//
// Phase schedule per iteration (2 K-tiles t0=buf0, t1=buf1):
//  ph1 c(b0,mh0,nh0) stage A-H1(t1->b1), B-H1(t1->b1)
//  ph2 c(b0,mh0,nh1) -
//  ph3 c(b0,mh1,nh0) stage A-H0(t0+2->b0)
//  ph4 c(b0,mh1,nh1) stage B-H0(t0+2->b0), vmcnt(4)
//  ph5 c(b1,mh0,nh0) stage A-H1(t0+2->b0), B-H1(t0+2->b0)
//  ph6 c(b1,mh0,nh1) -
//  ph7 c(b1,mh1,nh0) stage A-H0(t1+2->b1)
//  ph8 c(b1,mh1,nh1) stage B-H0(t1+2->b1), vmcnt(4)
// Every stage is issued >=1 phase after its region's last read (overwrite-
// safe), every consumption is covered by a prior vmcnt(4)+barrier.
// ============================================================================

#define QKV_K 2048

#define STA(BUF, G, KB) do { \
    const unsigned short* s_ = Ab + (size_t)(m0 + 16 * (G)) * QKV_K + (KB) + laneoff; \
    unsigned short* d_ = &sA[BUF][(G) * 1024]; \
    ld_lds16(s_, d_); ld_lds16(s_ + 32, d_ + 512); \
} while (0)

#define STB(BUF, G, KB) do { \
    const unsigned short* s_ = Bb + (size_t)(n0 + 16 * (G)) * QKV_K + (KB) + laneoff; \
    unsigned short* d_ = &sB[BUF][(G) * 1024]; \
    ld_lds16(s_, d_); ld_lds16(s_ + 32, d_ + 512); \
} while (0)

#define PH(BUF, MH, NH, VM, ...) do { \
    FragU a_[4][2], b_[2][2]; \
    _Pragma("unroll") \
    for (int i2 = 0; i2 < 4; ++i2) { \
        const int gg = wr8 + (MH) * 4 + i2; \
        a_[i2][0].u = *(const uint4*)&sA[BUF][gg * 1024 + ro]; \
        a_[i2][1].u = *(const uint4*)&sA[BUF][gg * 1024 + 512 + ro]; \
    } \
    _Pragma("unroll") \
    for (int j2 = 0; j2 < 2; ++j2) { \
        const int gg = wc4 + (NH) * 2 + j2; \
        b_[j2][0].u = *(const uint4*)&sB[BUF][gg * 1024 + ro]; \
        b_[j2][1].u = *(const uint4*)&sB[BUF][gg * 1024 + 512 + ro]; \
    } \
    __VA_ARGS__; \
    if (VM) asm volatile("s_waitcnt vmcnt(4)" ::: "memory"); \
    __builtin_amdgcn_s_barrier(); \
    asm volatile("s_waitcnt lgkmcnt(0)" ::: "memory"); \
    __builtin_amdgcn_s_setprio(1); \
    _Pragma("unroll") \
    for (int i2 = 0; i2 < 4; ++i2) { \
        _Pragma("unroll") \
        for (int j2 = 0; j2 < 2; ++j2) { \
            acc[(MH) * 4 + i2][(NH) * 2 + j2] = __builtin_amdgcn_mfma_f32_16x16x32_bf16( \
                a_[i2][0].b, b_[j2][0].b, acc[(MH) * 4 + i2][(NH) * 2 + j2], 0, 0, 0); \
            acc[(MH) * 4 + i2][(NH) * 2 + j2] = __builtin_amdgcn_mfma_f32_16x16x32_bf16( \
                a_[i2][1].b, b_[j2][1].b, acc[(MH) * 4 + i2][(NH) * 2 + j2], 0, 0, 0); \
        } \
    } \
    __builtin_amdgcn_s_setprio(0); \
    __builtin_amdgcn_s_barrier(); \
} while (0)

__global__ __launch_bounds__(512, 2)
void gemm_qkv256(const unsigned short* __restrict__ Ab, const unsigned short* __restrict__ Bb,
                 const float* __restrict__ bq, const float* __restrict__ bk,
                 const float* __restrict__ bv,
                 unsigned short* __restrict__ qo, unsigned short* __restrict__ ko,
                 unsigned short* __restrict__ vo) {
    __shared__ __align__(16) unsigned short sA[2][16384];
    __shared__ __align__(16) unsigned short sB[2][16384];

    // bijective XCD swizzle: 384 blocks = 8 XCDs x 48, m-major within XCD
    int id = blockIdx.y * 12 + blockIdx.x;
    id = (id & 7) * 48 + (id >> 3);
    const int m0 = (id / 12) * 256;
    const int n0 = (id % 12) * 256;

    const int t = threadIdx.x;
    const int w = t >> 6, l = t & 63;
    const int lm = l & 15, quad = l >> 4;
    const int wr = w >> 2, wc = w & 3;          // wave grid 2(M) x 4(N)
    const int wr8 = wr * 8, wc4 = wc * 4;
    const int ro = quad * 128 + lm * 8;         // frag read offset (ushorts)
    const size_t laneoff = (size_t)lm * QKV_K + 8 * quad;

    // per-wave stage group ids
    const int gA0 = (w & 3) + ((w >> 2) << 3);  // H0A: {0..3, 8..11}
    const int gA1 = gA0 + 4;                    // H1A: {4..7, 12..15}
    const int gB0 = (w & 1) + ((w >> 1) << 2);  // H0B: {0,1,4,5,8,9,12,13}
    const int gB1 = gB0 + 2;                    // H1B: {2,3,6,7,10,11,14,15}

    floatx4 acc[8][4];
    #pragma unroll
    for (int i = 0; i < 8; ++i)
        #pragma unroll
        for (int j = 0; j < 4; ++j)
            acc[i][j] = (floatx4)(0.f);

    // prologue: tile0 fully into buf0, tile1 H0 into buf1
    STA(0, gA0, 0); STA(0, gA1, 0);
    STB(0, gB0, 0); STB(0, gB1, 0);
    STA(1, gA0, 64); STB(1, gB0, 64);
    asm volatile("s_waitcnt vmcnt(4)" ::: "memory");   // tile0's 8 instrs done
    __builtin_amdgcn_s_barrier();

    #pragma unroll 1
    for (int kb = 0; kb < QKV_K; kb += 128) {
        const int kn = (kb + 128 < QKV_K) ? (kb + 128) : kb;  // clamped (restage = same bytes)
        PH(0, 0, 0, 0, STA(1, gA1, kb + 64); STB(1, gB1, kb + 64));
        PH(0, 0, 1, 0, (void)0);
        PH(0, 1, 0, 0, STA(0, gA0, kn));
        PH(0, 1, 1, 1, STB(0, gB0, kn));
        PH(1, 0, 0, 0, STA(0, gA1, kn); STB(0, gB1, kn));
        PH(1, 0, 1, 0, (void)0);
        PH(1, 1, 0, 0, STA(1, gA0, kn + 64));
        PH(1, 1, 1, 1, STB(1, gB0, kn + 64));
    }
    // drain all outstanding LDS-DMA before epilogue / endpgm (the clamped
    // restages of the last iteration are never consumed -> must not be
    // in flight at s_endpgm).
    asm volatile("s_waitcnt vmcnt(0)" ::: "memory");

    // epilogue: each block lies entirely within one projection (1024 % 256 == 0)
    const int proj = n0 >> 10;
    unsigned short* Cb = proj == 0 ? qo : (proj == 1 ? ko : vo);
    const float* bias  = proj == 0 ? bq : (proj == 1 ? bk : bv);
    const int ndb = (n0 & 1023) + wc * 64;
    #pragma unroll
    for (int j = 0; j < 4; ++j) {
        const int d = ndb + j * 16 + lm;
        const float bj = bias[d];
        #pragma unroll
        for (int i = 0; i < 8; ++i) {
            const int row0 = m0 + wr * 128 + i * 16 + quad * 4;
            #pragma unroll
            for (int r = 0; r < 4; ++r)
                Cb[(size_t)(row0 + r) * 1024 + d] = f2bf(acc[i][j][r] + bj);
        }
    }
}

// Output projection: A=attn bf16 [8192][1024], B=wob [1024][1024]. fp32 out.
__global__ __launch_bounds__(256)
void gemm_out(const unsigned short* __restrict__ A, const unsigned short* __restrict__ B,
              const float* __restrict__ bo, float* __restrict__ C) {
    __shared__ __align__(16) unsigned short As[128 * 32];
    __shared__ __align__(16) unsigned short Bs[128 * 32];
    const int m0 = blockIdx.y * 128;
    const int n0 = blockIdx.x * 128;
    floatx4 acc[4][4];
    #pragma unroll
    for (int i = 0; i < 4; ++i)
        #pragma unroll
        for (int j = 0; j < 4; ++j)
            acc[i][j] = (floatx4)(0.f);
    mfma_core<1024>(A, B, m0, n0, As, Bs, acc);

    const int t = threadIdx.x;
    const int w = t >> 6, l = t & 63;
    const int wm = (w >> 1) * 64, wn = (w & 1) * 64;
    const int lm = l & 15, lq = l >> 4;
    #pragma unroll
    for (int j = 0; j < 4; ++j) {
        const int col = n0 + wn + j * 16 + lm;
        const float bj = bo[col];
        #pragma unroll
        for (int i = 0; i < 4; ++i) {
            #pragma unroll
            for (int r = 0; r < 4; ++r) {
                const int row = m0 + wm + i * 16 + lq * 4 + r;
                C[(size_t)row * EE + col] = acc[i][j][r] + bj;
            }
        }
    }
}

// ---- Stage 1 (MFMA): Sk[d][e] = sum_s sigma_k[s][d]*v[s][e], z[d]=colsum(sigma_k).
__global__ __launch_bounds__(256)
void seg_kv(const unsigned short* __restrict__ k, const unsigned short* __restrict__ v,
            float* __restrict__ Skv, float* __restrict__ zc) {
    __shared__ __align__(16) unsigned short KT[64 * 72];  // sigma_k^T [d][s]
    __shared__ __align__(16) unsigned short VT[64 * 72];  // v^T       [e][s]
    const int t = threadIdx.x;
    const int w = t >> 6, l = t & 63, quad = l >> 4, lm = l & 15;
    const size_t base = (size_t)blockIdx.x * 4096;

    #pragma unroll
    for (int i = 0; i < 2; ++i) {
        const int c  = t + i * 256;            // uint4 chunk
        const int sr = c >> 3, c0 = (c & 7) * 8;
        const uint4 pk = *(const uint4*)(k + base + c * 8);
        const uint4 pv = *(const uint4*)(v + base + c * 8);
        float4 f0, f1;
        unp8(pk, f0, f1);
        KT[(c0 + 0) * 72 + sr] = f2bf(elu1(f0.x));
        KT[(c0 + 1) * 72 + sr] = f2bf(elu1(f0.y));
        KT[(c0 + 2) * 72 + sr] = f2bf(elu1(f0.z));
        KT[(c0 + 3) * 72 + sr] = f2bf(elu1(f0.w));
        KT[(c0 + 4) * 72 + sr] = f2bf(elu1(f1.x));
        KT[(c0 + 5) * 72 + sr] = f2bf(elu1(f1.y));
        KT[(c0 + 6) * 72 + sr] = f2bf(elu1(f1.z));
        KT[(c0 + 7) * 72 + sr] = f2bf(elu1(f1.w));
        const unsigned short* pvs = (const unsigned short*)&pv;
        #pragma unroll
        for (int jj = 0; jj < 8; ++jj) VT[(c0 + jj) * 72 + sr] = pvs[jj];
    }
    __syncthreads();

    if (t < 64) {                                  // z[d] = rowsum of KT row d
        float ssum = 0.f;
        #pragma unroll
        for (int c2 = 0; c2 < 8; ++c2) {
            const uint4 p = *(const uint4*)&KT[t * 72 + c2 * 8];
            float4 a, b;
            unp8(p, a, b);
            ssum += a.x + a.y + a.z + a.w + b.x + b.y + b.z + b.w;
        }
        zc[(size_t)blockIdx.x * 64 + t] = ssum;
    }

    FragU ak0, ak1;
    ak0.u = *(const uint4*)&KT[(16 * w + lm) * 72 + quad * 8];
    ak1.u = *(const uint4*)&KT[(16 * w + lm) * 72 + 32 + quad * 8];
    floatx4 C4[4];
    #pragma unroll
    for (int j = 0; j < 4; ++j) C4[j] = (floatx4)(0.f);
    #pragma unroll
    for (int j = 0; j < 4; ++j) {
        FragU b0, b1;
        b0.u = *(const uint4*)&VT[(j * 16 + lm) * 72 + quad * 8];
        b1.u = *(const uint4*)&VT[(j * 16 + lm) * 72 + 32 + quad * 8];
        C4[j] = __builtin_amdgcn_mfma_f32_16x16x32_bf16(ak0.b, b0.b, C4[j], 0, 0, 0);
        C4[j] = __builtin_amdgcn_mfma_f32_16x16x32_bf16(ak1.b, b1.b, C4[j], 0, 0, 0);
    }
    const int d0 = 16 * w + quad * 4;
    #pragma unroll
    for (int j = 0; j < 4; ++j)
        #pragma unroll
        for (int r = 0; r < 4; ++r)
            Skv[base + (size_t)(d0 + r) * 64 + j * 16 + lm] = C4[j][r];
}

// ---- Stage 2: exclusive prefix over 16 segments per (b,h) chain.
__global__ __launch_bounds__(256)
void prefix_mem(float* __restrict__ Skv, float* __restrict__ zc) {
    const int t  = threadIdx.x;
    const int bh = blockIdx.y;
    float* p0 = Skv + (size_t)bh * 16 * 4096 + blockIdx.x * 512 + t * 2;
    float2 acc = make_float2(0.f, 0.f);
    #pragma unroll
    for (int n = 0; n < 16; ++n) {
        float2* p = (float2*)(p0 + (size_t)n * 4096);
        const float2 tmp = *p;
        *p = acc;
        acc.x += tmp.x; acc.y += tmp.y;
    }
    if (blockIdx.x == 0 && t < 64) {
        float* zp0 = zc + (size_t)bh * 16 * 64 + t;
        float za = 0.f;
        #pragma unroll
        for (int n = 0; n < 16; ++n) {
            float* zp = zp0 + n * 64;
            const float tmp = *zp;
            *zp = za;
            za += tmp;
        }
    }
}

// ---- Stage 3 (MFMA): per-segment attention.
__global__ __launch_bounds__(256)
void seg_attn(const unsigned short* __restrict__ q, const unsigned short* __restrict__ k,
              const unsigned short* __restrict__ v, const float* __restrict__ memp,
              const float* __restrict__ zp, const float* __restrict__ beta,
              unsigned short* __restrict__ ab) {
    __shared__ __align__(16) unsigned short Pb[64 * 72];  // P bf16 [s][t]
    __shared__ __align__(16) unsigned short VT[64 * 72];  // v^T    [e][s]
    __shared__ __align__(16) unsigned short MT[64 * 72];  // mem^T  [e][d]
    __shared__ float rs[64];
    __shared__ float zr[64];
    const int t = threadIdx.x;
    const int w = t >> 6, l = t & 63, quad = l >> 4, lm = l & 15;
    const int seg = blockIdx.x;
    const int h   = (seg >> 4) & 15;
    const float gate = 1.f / (1.f + __expf(-10.f * beta[h]));
    const float omg  = 1.f - gate;
    const size_t base = (size_t)seg * 4096;

    // stage v^T
    #pragma unroll
    for (int i = 0; i < 2; ++i) {
        const int c  = t + i * 256;
        const int sr = c >> 3, c0 = (c & 7) * 8;
        const uint4 pv = *(const uint4*)(v + base + c * 8);
        const unsigned short* pvs = (const unsigned short*)&pv;
        #pragma unroll
        for (int jj = 0; jj < 8; ++jj) VT[(c0 + jj) * 72 + sr] = pvs[jj];
    }
    // stage mem^T (fp32 -> bf16)
    #pragma unroll
    for (int i = 0; i < 4; ++i) {
        const int c = t + i * 256;               // float4 chunk
        const int d = c >> 4, e0 = (c & 15) * 4;
        const float4 m4 = *(const float4*)(memp + base + c * 4);
        MT[(e0 + 0) * 72 + d] = f2bf(m4.x);
        MT[(e0 + 1) * 72 + d] = f2bf(m4.y);
        MT[(e0 + 2) * 72 + d] = f2bf(m4.z);
        MT[(e0 + 3) * 72 + d] = f2bf(m4.w);
    }
    // rs[s] = rowsum(sigma_q): quarter-row per thread + shfl reduce
    {
        const int s = t >> 2, dq = (t & 3) * 16;
        const uint4 a0 = *(const uint4*)(q + base + s * 64 + dq);
        const uint4 a1 = *(const uint4*)(q + base + s * 64 + dq + 8);
        float4 f0, f1, f2, f3;
        unp8(a0, f0, f1); unp8(a1, f2, f3);
        float p = elu1(f0.x) + elu1(f0.y) + elu1(f0.z) + elu1(f0.w)
                + elu1(f1.x) + elu1(f1.y) + elu1(f1.z) + elu1(f1.w)
                + elu1(f2.x) + elu1(f2.y) + elu1(f2.z) + elu1(f2.w)
                + elu1(f3.x) + elu1(f3.y) + elu1(f3.z) + elu1(f3.w);
        p += __shfl_xor(p, 1, 64);
        p += __shfl_xor(p, 2, 64);
        if ((t & 3) == 0) rs[s] = p;
    }
    if (t < 64) zr[t] = zp[(size_t)seg * 64 + t];
    __syncthreads();

    // ---- scores: wave w computes rows [16w,16w+16) x all 64 cols
    const unsigned short* qrow = q + base + (size_t)(16 * w + lm) * 64;
    FragU aq0, aq1;
    aq0.u = *(const uint4*)(qrow + quad * 8);
    aq1.u = *(const uint4*)(qrow + 32 + quad * 8);
    floatx4 S[4];
    #pragma unroll
    for (int j = 0; j < 4; ++j) S[j] = (floatx4)(0.f);
    #pragma unroll
    for (int j = 0; j < 4; ++j) {
        const unsigned short* krow = k + base + (size_t)(j * 16 + lm) * 64;
        FragU b0, b1;
        b0.u = *(const uint4*)(krow + quad * 8);
        b1.u = *(const uint4*)(krow + 32 + quad * 8);
        S[j] = __builtin_amdgcn_mfma_f32_16x16x32_bf16(aq0.b, b0.b, S[j], 0, 0, 0);
        S[j] = __builtin_amdgcn_mfma_f32_16x16x32_bf16(aq1.b, b1.b, S[j], 0, 0, 0);
    }
    // ---- causal softmax in C-layout registers; write P bf16 to LDS
    const int srow0 = 16 * w + quad * 4;
    #pragma unroll
    for (int r = 0; r < 4; ++r) {
        const int s_g = srow0 + r;
        float m = -3.0e38f;
        #pragma unroll
        for (int j = 0; j < 4; ++j) {
            const int t_g = j * 16 + lm;
            const float val = (t_g <= s_g) ? S[j][r] * 0.125f : -3.0e38f;
            S[j][r] = val;
            m = fmaxf(m, val);
        }
        m = fmaxf(m, __shfl_xor(m, 1, 64));
        m = fmaxf(m, __shfl_xor(m, 2, 64));
        m = fmaxf(m, __shfl_xor(m, 4, 64));
        m = fmaxf(m, __shfl_xor(m, 8, 64));
        float ss = 0.f;
        #pragma unroll
        for (int j = 0; j < 4; ++j) {
            const int t_g = j * 16 + lm;
            const float e = (t_g <= s_g) ? __expf(S[j][r] - m) : 0.f;
            S[j][r] = e;
            ss += e;
        }
        ss += __shfl_xor(ss, 1, 64);
        ss += __shfl_xor(ss, 2, 64);
        ss += __shfl_xor(ss, 4, 64);
        ss += __shfl_xor(ss, 8, 64);
        const float inv = 1.f / ss;
        #pragma unroll
        for (int j = 0; j < 4; ++j)
            Pb[s_g * 72 + j * 16 + lm] = f2bf(S[j][r] * inv);
    }
    __syncthreads();

    // ---- A_dot = P@V and A_mem = sigma_q@mem (both C-layout accumulators)
    FragU ap0, ap1, as0, as1;
    ap0.u = *(const uint4*)&Pb[(16 * w + lm) * 72 + quad * 8];
    ap1.u = *(const uint4*)&Pb[(16 * w + lm) * 72 + 32 + quad * 8];
    {
        float4 f0, f1, f2, f3;
        unp8(aq0.u, f0, f1);
        unp8(aq1.u, f2, f3);
        f0.x = elu1(f0.x); f0.y = elu1(f0.y); f0.z = elu1(f0.z); f0.w = elu1(f0.w);
        f1.x = elu1(f1.x); f1.y = elu1(f1.y); f1.z = elu1(f1.z); f1.w = elu1(f1.w);
        f2.x = elu1(f2.x); f2.y = elu1(f2.y); f2.z = elu1(f2.z); f2.w = elu1(f2.w);
        f3.x = elu1(f3.x); f3.y = elu1(f3.y); f3.z = elu1(f3.z); f3.w = elu1(f3.w);
        as0.u = pack8bf(f0, f1);
        as1.u = pack8bf(f2, f3);
    }
    floatx4 AD[4], AM[4];
    #pragma unroll
    for (int j = 0; j < 4; ++j) { AD[j] = (floatx4)(0.f); AM[j] = (floatx4)(0.f); }
    #pragma unroll
    for (int j = 0; j < 4; ++j) {
        FragU bv0, bv1, bm0, bm1;
        bv0.u = *(const uint4*)&VT[(j * 16 + lm) * 72 + quad * 8];
        bv1.u = *(const uint4*)&VT[(j * 16 + lm) * 72 + 32 + quad * 8];
        bm0.u = *(const uint4*)&MT[(j * 16 + lm) * 72 + quad * 8];
        bm1.u = *(const uint4*)&MT[(j * 16 + lm) * 72 + 32 + quad * 8];
        AD[j] = __builtin_amdgcn_mfma_f32_16x16x32_bf16(ap0.b, bv0.b, AD[j], 0, 0, 0);
        AD[j] = __builtin_amdgcn_mfma_f32_16x16x32_bf16(ap1.b, bv1.b, AD[j], 0, 0, 0);
        AM[j] = __builtin_amdgcn_mfma_f32_16x16x32_bf16(as0.b, bm0.b, AM[j], 0, 0, 0);
        AM[j] = __builtin_amdgcn_mfma_f32_16x16x32_bf16(as1.b, bm1.b, AM[j], 0, 0, 0);
    }
    // ---- combine + store attn bf16
    #pragma unroll
    for (int j = 0; j < 4; ++j) {
        const int d = j * 16 + lm;
        const float zd = zr[d];
        #pragma unroll
        for (int r = 0; r < 4; ++r) {
            const int s_g = srow0 + r;
            const float den = rs[s_g] * zd + 1e-6f;
            const float o = gate * (AM[j][r] / den) + omg * AD[j][r];
            ab[base + (size_t)s_g * 64 + d] = f2bf(o);
        }
    }
}

extern "C" void kernel_launch(void* const* d_in, const int* in_sizes, int n_in,
                              void* d_out, int out_size, void* d_ws, size_t ws_size,
                              hipStream_t stream) {
    const float* x    = (const float*)d_in[0];
    const float* Wq   = (const float*)d_in[1];
    const float* bq   = (const float*)d_in[2];
    const float* Wk   = (const float*)d_in[3];
    const float* bk   = (const float*)d_in[4];
    const float* Wv   = (const float*)d_in[5];
    const float* bv   = (const float*)d_in[6];
    const float* Wo   = (const float*)d_in[7];
    const float* bo   = (const float*)d_in[8];
    const float* beta = (const float*)d_in[9];
    float* out = (float*)d_out;

    unsigned char* wsb = (unsigned char*)d_ws;
    unsigned short* xb  = (unsigned short*)(wsb);                       // 32 MB; reused as ab
    unsigned short* wb  = (unsigned short*)(wsb + (32ull << 20));       // 12 MB  [3072][2048]
    unsigned short* wob = (unsigned short*)(wsb + (44ull << 20));       // 2 MB   [1024][1024]
    unsigned short* qb  = (unsigned short*)(wsb + (46ull << 20));       // 16 MB
    unsigned short* kb  = (unsigned short*)(wsb + (62ull << 20));       // 16 MB
    unsigned short* vb  = (unsigned short*)(wsb + (78ull << 20));       // 16 MB
    float* Skv = (float*)(wsb + (94ull << 20));                         // 32 MB
    float* zc  = (float*)(wsb + (126ull << 20));                        // 0.5 MB
    unsigned short* ab = xb;   // attn bf16 (xb dead after gemm_qkv)

    cvt_bf16<<<8192, 256, 0, stream>>>(x, xb, 2097152);
    cvt_w<<<3584, 256, 0, stream>>>(Wq, Wk, Wv, Wo, wb, wob);

    gemm_qkv256<<<dim3(12, 32), 512, 0, stream>>>(xb, wb, bq, bk, bv, qb, kb, vb);
    seg_kv<<<2048, 256, 0, stream>>>(kb, vb, Skv, zc);
    prefix_mem<<<dim3(8, 128), 256, 0, stream>>>(Skv, zc);
    seg_attn<<<2048, 256, 0, stream>>>(qb, kb, vb, Skv, zc, beta, ab);
    gemm_out<<<dim3(8, 64), 256, 0, stream>>>(ab, wob, bo, out);
}

// Round 3
// 395.738 us; speedup vs baseline: 1.1142x; 1.1142x over previous
//
#include <hip/hip_runtime.h>
#include <hip/hip_bf16.h>
#include <cstddef>

#define EE 1024            // E
#define MTOT 8192          // B*E

using floatx4 = __attribute__((ext_vector_type(4))) float;
using bf16x8  = __attribute__((ext_vector_type(8))) __bf16;

union FragU { uint4 u; bf16x8 b; };

__device__ __forceinline__ float elu1(float x) {
    return x > 0.f ? x + 1.f : __expf(x);
}

__device__ __forceinline__ unsigned int pack2bf(float x, float y) {
    __hip_bfloat162 h = __float22bfloat162_rn(make_float2(x, y));
    union { __hip_bfloat162 h; unsigned int u; } c;
    c.h = h;
    return c.u;
}

__device__ __forceinline__ uint4 pack8bf(const float4 a, const float4 b) {
    uint4 r;
    r.x = pack2bf(a.x, a.y); r.y = pack2bf(a.z, a.w);
    r.z = pack2bf(b.x, b.y); r.w = pack2bf(b.z, b.w);
    return r;
}

__device__ __forceinline__ unsigned short f2bf(float x) {
    union { __hip_bfloat16 h; unsigned short s; } c;
    c.h = __float2bfloat16(x);
    return c.s;
}

__device__ __forceinline__ void unp8(const uint4 p, float4& a, float4& b) {
    a.x = __uint_as_float(p.x << 16); a.y = __uint_as_float(p.x & 0xffff0000u);
    a.z = __uint_as_float(p.y << 16); a.w = __uint_as_float(p.y & 0xffff0000u);
    b.x = __uint_as_float(p.z << 16); b.y = __uint_as_float(p.z & 0xffff0000u);
    b.z = __uint_as_float(p.w << 16); b.w = __uint_as_float(p.w & 0xffff0000u);
}

// fp32 -> bf16 bulk convert, 8 elems/thread
__global__ __launch_bounds__(256)
void cvt_bf16(const float* __restrict__ src, unsigned short* __restrict__ dst, int n8) {
    const int i = blockIdx.x * 256 + threadIdx.x;
    if (i >= n8) return;
    const float4 a = ((const float4*)src)[2 * i];
    const float4 b = ((const float4*)src)[2 * i + 1];
    ((uint4*)dst)[i] = pack8bf(a, b);
}

// All four weight matrices in one launch.
__global__ __launch_bounds__(256)
void cvt_w(const float* __restrict__ Wq, const float* __restrict__ Wk,
           const float* __restrict__ Wv, const float* __restrict__ Wo,
           unsigned short* __restrict__ wb, unsigned short* __restrict__ wob) {
    const int i = blockIdx.x * 256 + threadIdx.x;
    if (i >= 917504) return;
    const float* src;
    unsigned short* dst;
    int off;
    if (i < 262144)      { src = Wq; dst = wb;           off = i; }
    else if (i < 524288) { src = Wk; dst = wb + 2097152; off = i - 262144; }
    else if (i < 786432) { src = Wv; dst = wb + 4194304; off = i - 524288; }
    else                 { src = Wo; dst = wob;          off = i - 786432; }
    const float4 a = ((const float4*)src)[2 * off];
    const float4 b = ((const float4*)src)[2 * off + 1];
    ((uint4*)dst)[off] = pack8bf(a, b);
}

// ============================================================================
// 128x256 phase-split GEMM core. A[M][K] bf16, B[N][K]^T bf16 (row-major B^T).
// 8 waves (2m x 4n), per-wave 64x64 output, BK=64, double-buffered 96 KiB LDS.
//
// LDS layout per K-step tile: 16-row groups; group g stored as
//   [2 k-halves][4 col-chunks(16B)][16 rows] -> ushort off =
//   g*1024 + kh*512 + cb*128 + r*8.
// Frag ds_read_b128 (lane lm,quad): byte = g*2048 + kh*1024 + quad*256 + lm*16
//   -> 64 lanes cover 1024 contiguous bytes -> ZERO bank conflicts (verified
//   round 2: SQ_LDS_BANK_CONFLICT = 0).
// Staging is REG-STAGED (not global_load_lds): global_load_dwordx4 with
//   lane l -> row l>>2, col (l&3)*8 (64-B coalesced runs, m97 pattern),
//   then ds_write_b128 to the lane's permuted LDS slot. Compiler-tracked
//   loads give precise counted vmcnt; load->ds_write distance ~4 phases.
//
// Per K-step s (buf p = s&1), two phases:
//   phA: ds_read A-frags(8)+B-low(4) from buf p; issue 6 global loads for
//        K-step s+2; barrier; lgkmcnt(0); 16 MFMA (n-frags 0,1); barrier.
//   phB: ds_read B-high(4) from buf p; ds_write the s+1 staging regs into
//        buf 1-p; barrier; lgkmcnt(0); 16 MFMA (n-frags 2,3); barrier.
// Register reuse: A-frags live across phA+phB (16 ds_read/K-step = minimum).
// ============================================================================

#define BARD() __builtin_amdgcn_s_barrier()
#define LGKM0() asm volatile("s_waitcnt lgkmcnt(0)" ::: "memory")

#define LOAD_SET(Pa0, Pa1, Pb0, Pb1, Pb2, Pb3, KS) do {                      \
    const size_t ko_ = (size_t)(KS) * 64;                                    \
    Pa0 = *(const uint4*)(Asrc + ko_);                                       \
    Pa1 = *(const uint4*)(Asrc + ko_ + 32);                                  \
    Pb0 = *(const uint4*)(Bsrc0 + ko_);                                      \
    Pb1 = *(const uint4*)(Bsrc0 + ko_ + 32);                                 \
    Pb2 = *(const uint4*)(Bsrc1 + ko_);                                      \
    Pb3 = *(const uint4*)(Bsrc1 + ko_ + 32);                                 \
} while (0)

#define WRITE_SET(Pa0, Pa1, Pb0, Pb1, Pb2, Pb3, sAp, sBp) do {               \
    *(uint4*)&sAp[w * 1024 + wo]             = Pa0;                          \
    *(uint4*)&sAp[w * 1024 + 512 + wo]       = Pa1;                          \
    *(uint4*)&sBp[(2 * w) * 1024 + wo]       = Pb0;                          \
    *(uint4*)&sBp[(2 * w) * 1024 + 512 + wo] = Pb1;                         \
    *(uint4*)&sBp[(2 * w + 1) * 1024 + wo]       = Pb2;                      \
    *(uint4*)&sBp[(2 * w + 1) * 1024 + 512 + wo] = Pb3;                      \
} while (0)

#define RD_A(sAp) do {                                                       \
    _Pragma("unroll")                                                        \
    for (int i2 = 0; i2 < 4; ++i2) {                                         \
        A8[i2][0].u = *(const uint4*)&sAp[(wr4 + i2) * 1024 + ro];           \
        A8[i2][1].u = *(const uint4*)&sAp[(wr4 + i2) * 1024 + 512 + ro];     \
    }                                                                        \
} while (0)

#define RD_BL(sBp) do {                                                      \
    _Pragma("unroll")                                                        \
    for (int j2 = 0; j2 < 2; ++j2) {                                         \
        Bl[j2][0].u = *(const uint4*)&sBp[(wc4 + j2) * 1024 + ro];           \
        Bl[j2][1].u = *(const uint4*)&sBp[(wc4 + j2) * 1024 + 512 + ro];     \
    }                                                                        \
} while (0)

#define RD_BH(sBp) do {                                                      \
    _Pragma("unroll")                                                        \
    for (int j2 = 0; j2 < 2; ++j2) {                                         \
        Bh[j2][0].u = *(const uint4*)&sBp[(wc4 + 2 + j2) * 1024 + ro];       \
        Bh[j2][1].u = *(const uint4*)&sBp[(wc4 + 2 + j2) * 1024 + 512 + ro]; \
    }                                                                        \
} while (0)

#define MML() do {                                                           \
    __builtin_amdgcn_s_setprio(1);                                           \
    _Pragma("unroll")                                                        \
    for (int i2 = 0; i2 < 4; ++i2)                                           \
        _Pragma("unroll")                                                    \
        for (int j2 = 0; j2 < 2; ++j2) {                                     \
            acc[i2][j2] = __builtin_amdgcn_mfma_f32_16x16x32_bf16(           \
                A8[i2][0].b, Bl[j2][0].b, acc[i2][j2], 0, 0, 0);             \
            acc[i2][j2] = __builtin_amdgcn_mfma_f32_16x16x32_bf16(           \
                A8[i2][1].b, Bl[j2][1].b, acc[i2][j2], 0, 0, 0);             \
        }                                                                    \
    __builtin_amdgcn_s_setprio(0);                                           \
} while (0)

#define MMH() do {                                                           \
    __builtin_amdgcn_s_setprio(1);                                           \
    _Pragma("unroll")                                                        \
    for (int i2 = 0; i2 < 4; ++i2)                                           \
        _Pragma("unroll")                                                    \
        for (int j2 = 0; j2 < 2; ++j2) {                                     \
            acc[i2][2 + j2] = __builtin_amdgcn_mfma_f32_16x16x32_bf16(       \
                A8[i2][0].b, Bh[j2][0].b, acc[i2][2 + j2], 0, 0, 0);         \
            acc[i2][2 + j2] = __builtin_amdgcn_mfma_f32_16x16x32_bf16(       \
                A8[i2][1].b, Bh[j2][1].b, acc[i2][2 + j2], 0, 0, 0);         \
        }                                                                    \
    __builtin_amdgcn_s_setprio(0);                                           \
} while (0)

template<int KTOT>
__device__ __forceinline__ void gemm_core256(
    const unsigned short* __restrict__ A, const unsigned short* __restrict__ B,
    int m0, int n0,
    unsigned short* sA0, unsigned short* sA1,
    unsigned short* sB0, unsigned short* sB1,
    floatx4 (&acc)[4][4]) {
    const int t = threadIdx.x;
    const int w = t >> 6, l = t & 63;
    const int lm = l & 15, quad = l >> 4;
    const int wr4 = (w >> 2) * 4, wc4 = (w & 3) * 4;
    const int ro = quad * 128 + lm * 8;          // frag read offset (ushorts)
    const int ar = l >> 2, ac = (l & 3) * 8;     // staging source lane map
    const int wo = (l & 3) * 128 + ar * 8;       // staging LDS slot (ushorts)

    const unsigned short* Asrc  = A + (size_t)(m0 + 16 * w + ar) * KTOT + ac;
    const unsigned short* Bsrc0 = B + (size_t)(n0 + 32 * w + ar) * KTOT + ac;
    const unsigned short* Bsrc1 = B + (size_t)(n0 + 32 * w + 16 + ar) * KTOT + ac;

    FragU A8[4][2], Bl[2][2], Bh[2][2];
    uint4 Ga0, Ga1, Gb0, Gb1, Gb2, Gb3;   // staging set G (even K-steps)
    uint4 Ha0, Ha1, Hb0, Hb1, Hb2, Hb3;   // staging set H (odd K-steps)

    const int NS = KTOT / 64;

    // prologue: load s0->G, s1->H; write G -> buf0
    LOAD_SET(Ga0, Ga1, Gb0, Gb1, Gb2, Gb3, 0);
    LOAD_SET(Ha0, Ha1, Hb0, Hb1, Hb2, Hb3, 1);
    WRITE_SET(Ga0, Ga1, Gb0, Gb1, Gb2, Gb3, sA0, sB0);
    LGKM0();
    BARD();

    #pragma unroll 1
    for (int s = 0; s < NS; s += 2) {
        const int k2 = (s + 2 < NS) ? s + 2 : s;        // clamped refetch
        const int k3 = (s + 3 < NS) ? s + 3 : s + 1;
        // phA(s): buf0
        RD_A(sA0); RD_BL(sB0);
        LOAD_SET(Ga0, Ga1, Gb0, Gb1, Gb2, Gb3, k2);
        BARD(); LGKM0(); MML(); BARD();
        // phB(s): buf0, write s+1 (H) -> buf1
        RD_BH(sB0);
        WRITE_SET(Ha0, Ha1, Hb0, Hb1, Hb2, Hb3, sA1, sB1);
        BARD(); LGKM0(); MMH(); BARD();
        // phA(s+1): buf1
        RD_A(sA1); RD_BL(sB1);
        LOAD_SET(Ha0, Ha1, Hb0, Hb1, Hb2, Hb3, k3);
        BARD(); LGKM0(); MML(); BARD();
        // phB(s+1): buf1, write s+2 (G) -> buf0
        RD_BH(sB1);
        WRITE_SET(Ga0, Ga1, Gb0, Gb1, Gb2, Gb3, sA0, sB0);
        BARD(); LGKM0(); MMH(); BARD();
    }
}

// QKV projection: A=xb [8192][2048], B=wb [3072][2048] (Wq|Wk|Wv rows).
__global__ __launch_bounds__(512, 2)
void gemm_qkv256(const unsigned short* __restrict__ Ab, const unsigned short* __restrict__ Bb,
                 const float* __restrict__ bq, const float* __restrict__ bk,
                 const float* __restrict__ bv,
                 unsigned short* __restrict__ qo, unsigned short* __restrict__ ko,
                 unsigned short* __restrict__ vo) {
    __shared__ __align__(16) unsigned short sA[2][8192];
    __shared__ __align__(16) unsigned short sB[2][16384];

    // bijective XCD swizzle: 768 blocks = 8 XCDs x 96, m-grouped within XCD
    int id = blockIdx.y * 12 + blockIdx.x;
    id = (id & 7) * 96 + (id >> 3);
    const int m0 = (id / 12) * 128;
    const int n0 = (id % 12) * 256;

    floatx4 acc[4][4];
    #pragma unroll
    for (int i = 0; i < 4; ++i)
        #pragma unroll
        for (int j = 0; j < 4; ++j)
            acc[i][j] = (floatx4)(0.f);

    gemm_core256<2048>(Ab, Bb, m0, n0, sA[0], sA[1], sB[0], sB[1], acc);

    const int t = threadIdx.x;
    const int w = t >> 6, l = t & 63;
    const int lm = l & 15, quad = l >> 4;
    const int wr = w >> 2, wc = w & 3;
    // each 256-col n-panel lies within one projection (1024 % 256 == 0)
    const int proj = n0 >> 10;
    unsigned short* Cb = proj == 0 ? qo : (proj == 1 ? ko : vo);
    const float* bias  = proj == 0 ? bq : (proj == 1 ? bk : bv);
    const int ndb = (n0 & 1023) + wc * 64;
    #pragma unroll
    for (int j = 0; j < 4; ++j) {
        const int d = ndb + j * 16 + lm;
        const float bj = bias[d];
        #pragma unroll
        for (int i = 0; i < 4; ++i) {
            const int row0 = m0 + wr * 64 + i * 16 + quad * 4;
            #pragma unroll
            for (int r = 0; r < 4; ++r)
                Cb[(size_t)(row0 + r) * 1024 + d] = f2bf(acc[i][j][r] + bj);
        }
    }
}

// Output projection: A=attn bf16 [8192][1024], B=wob [1024][1024]. fp32 out.
__global__ __launch_bounds__(512, 2)
void gemm_out256(const unsigned short* __restrict__ Ab, const unsigned short* __restrict__ Bb,
                 const float* __restrict__ bo, float* __restrict__ C) {
    __shared__ __align__(16) unsigned short sA[2][8192];
    __shared__ __align__(16) unsigned short sB[2][16384];

    // 256 blocks = 8 XCDs x 32
    int id = blockIdx.y * 4 + blockIdx.x;
    id = (id & 7) * 32 + (id >> 3);
    const int m0 = (id / 4) * 128;
    const int n0 = (id % 4) * 256;

    floatx4 acc[4][4];
    #pragma unroll
    for (int i = 0; i < 4; ++i)
        #pragma unroll
        for (int j = 0; j < 4; ++j)
            acc[i][j] = (floatx4)(0.f);

    gemm_core256<1024>(Ab, Bb, m0, n0, sA[0], sA[1], sB[0], sB[1], acc);

    const int t = threadIdx.x;
    const int w = t >> 6, l = t & 63;
    const int lm = l & 15, quad = l >> 4;
    const int wr = w >> 2, wc = w & 3;
    #pragma unroll
    for (int j = 0; j < 4; ++j) {
        const int col = n0 + wc * 64 + j * 16 + lm;
        const float bj = bo[col];
        #pragma unroll
        for (int i = 0; i < 4; ++i) {
            const int row0 = m0 + wr * 64 + i * 16 + quad * 4;
            #pragma unroll
            for (int r = 0; r < 4; ++r)
                C[(size_t)(row0 + r) * EE + col] = acc[i][j][r] + bj;
        }
    }
}

// ---- Stage 1 (MFMA): Sk[d][e] = sum_s sigma_k[s][d]*v[s][e], z[d]=colsum(sigma_k).
__global__ __launch_bounds__(256)
void seg_kv(const unsigned short* __restrict__ k, const unsigned short* __restrict__ v,
            float* __restrict__ Skv, float* __restrict__ zc) {
    __shared__ __align__(16) unsigned short KT[64 * 72];  // sigma_k^T [d][s]
    __shared__ __align__(16) unsigned short VT[64 * 72];  // v^T       [e][s]
    const int t = threadIdx.x;
    const int w = t >> 6, l = t & 63, quad = l >> 4, lm = l & 15;
    const size_t base = (size_t)blockIdx.x * 4096;

    #pragma unroll
    for (int i = 0; i < 2; ++i) {
        const int c  = t + i * 256;            // uint4 chunk
        const int sr = c >> 3, c0 = (c & 7) * 8;
        const uint4 pk = *(const uint4*)(k + base + c * 8);
        const uint4 pv = *(const uint4*)(v + base + c * 8);
        float4 f0, f1;
        unp8(pk, f0, f1);
        KT[(c0 + 0) * 72 + sr] = f2bf(elu1(f0.x));
        KT[(c0 + 1) * 72 + sr] = f2bf(elu1(f0.y));
        KT[(c0 + 2) * 72 + sr] = f2bf(elu1(f0.z));
        KT[(c0 + 3) * 72 + sr] = f2bf(elu1(f0.w));
        KT[(c0 + 4) * 72 + sr] = f2bf(elu1(f1.x));
        KT[(c0 + 5) * 72 + sr] = f2bf(elu1(f1.y));
        KT[(c0 + 6) * 72 + sr] = f2bf(elu1(f1.z));
        KT[(c0 + 7) * 72 + sr] = f2bf(elu1(f1.w));
        const unsigned short* pvs = (const unsigned short*)&pv;
        #pragma unroll
        for (int jj = 0; jj < 8; ++jj) VT[(c0 + jj) * 72 + sr] = pvs[jj];
    }
    __syncthreads();

    if (t < 64) {                                  // z[d] = rowsum of KT row d
        float ssum = 0.f;
        #pragma unroll
        for (int c2 = 0; c2 < 8; ++c2) {
            const uint4 p = *(const uint4*)&KT[t * 72 + c2 * 8];
            float4 a, b;
            unp8(p, a, b);
            ssum += a.x + a.y + a.z + a.w + b.x + b.y + b.z + b.w;
        }
        zc[(size_t)blockIdx.x * 64 + t] = ssum;
    }

    FragU ak0, ak1;
    ak0.u = *(const uint4*)&KT[(16 * w + lm) * 72 + quad * 8];
    ak1.u = *(const uint4*)&KT[(16 * w + lm) * 72 + 32 + quad * 8];
    floatx4 C4[4];
    #pragma unroll
    for (int j = 0; j < 4; ++j) C4[j] = (floatx4)(0.f);
    #pragma unroll
    for (int j = 0; j < 4; ++j) {
        FragU b0, b1;
        b0.u = *(const uint4*)&VT[(j * 16 + lm) * 72 + quad * 8];
        b1.u = *(const uint4*)&VT[(j * 16 + lm) * 72 + 32 + quad * 8];
        C4[j] = __builtin_amdgcn_mfma_f32_16x16x32_bf16(ak0.b, b0.b, C4[j], 0, 0, 0);
        C4[j] = __builtin_amdgcn_mfma_f32_16x16x32_bf16(ak1.b, b1.b, C4[j], 0, 0, 0);
    }
    const int d0 = 16 * w + quad * 4;
    #pragma unroll
    for (int j = 0; j < 4; ++j)
        #pragma unroll
        for (int r = 0; r < 4; ++r)
            Skv[base + (size_t)(d0 + r) * 64 + j * 16 + lm] = C4[j][r];
}

// ---- Stage 2: exclusive prefix over 16 segments per (b,h) chain.
__global__ __launch_bounds__(256)
void prefix_mem(float* __restrict__ Skv, float* __restrict__ zc) {
    const int t  = threadIdx.x;
    const int bh = blockIdx.y;
    float* p0 = Skv + (size_t)bh * 16 * 4096 + blockIdx.x * 512 + t * 2;
    float2 acc = make_float2(0.f, 0.f);
    #pragma unroll
    for (int n = 0; n < 16; ++n) {
        float2* p = (float2*)(p0 + (size_t)n * 4096);
        const float2 tmp = *p;
        *p = acc;
        acc.x += tmp.x; acc.y += tmp.y;
    }
    if (blockIdx.x == 0 && t < 64) {
        float* zp0 = zc + (size_t)bh * 16 * 64 + t;
        float za = 0.f;
        #pragma unroll
        for (int n = 0; n < 16; ++n) {
            float* zp = zp0 + n * 64;
            const float tmp = *zp;
            *zp = za;
            za += tmp;
        }
    }
}

// ---- Stage 3 (MFMA): per-segment attention.
__global__ __launch_bounds__(256)
void seg_attn(const unsigned short* __restrict__ q, const unsigned short* __restrict__ k,
              const unsigned short* __restrict__ v, const float* __restrict__ memp,
              const float* __restrict__ zp, const float* __restrict__ beta,
              unsigned short* __restrict__ ab) {
    __shared__ __align__(16) unsigned short Pb[64 * 72];  // P bf16 [s][t]
    __shared__ __align__(16) unsigned short VT[64 * 72];  // v^T    [e][s]
    __shared__ __align__(16) unsigned short MT[64 * 72];  // mem^T  [e][d]
    __shared__ float rs[64];
    __shared__ float zr[64];
    const int t = threadIdx.x;
    const int w = t >> 6, l = t & 63, quad = l >> 4, lm = l & 15;
    const int seg = blockIdx.x;
    const int h   = (seg >> 4) & 15;
    const float gate = 1.f / (1.f + __expf(-10.f * beta[h]));
    const float omg  = 1.f - gate;
    const size_t base = (size_t)seg * 4096;

    // stage v^T
    #pragma unroll
    for (int i = 0; i < 2; ++i) {
        const int c  = t + i * 256;
        const int sr = c >> 3, c0 = (c & 7) * 8;
        const uint4 pv = *(const uint4*)(v + base + c * 8);
        const unsigned short* pvs = (const unsigned short*)&pv;
        #pragma unroll
        for (int jj = 0; jj < 8; ++jj) VT[(c0 + jj) * 72 + sr] = pvs[jj];
    }
    // stage mem^T (fp32 -> bf16)
    #pragma unroll
    for (int i = 0; i < 4; ++i) {
        const int c = t + i * 256;               // float4 chunk
        const int d = c >> 4, e0 = (c & 15) * 4;
        const float4 m4 = *(const float4*)(memp + base + c * 4);
        MT[(e0 + 0) * 72 + d] = f2bf(m4.x);
        MT[(e0 + 1) * 72 + d] = f2bf(m4.y);
        MT[(e0 + 2) * 72 + d] = f2bf(m4.z);
        MT[(e0 + 3) * 72 + d] = f2bf(m4.w);
    }
    // rs[s] = rowsum(sigma_q): quarter-row per thread + shfl reduce
    {
        const int s = t >> 2, dq = (t & 3) * 16;
        const uint4 a0 = *(const uint4*)(q + base + s * 64 + dq);
        const uint4 a1 = *(const uint4*)(q + base + s * 64 + dq + 8);
        float4 f0, f1, f2, f3;
        unp8(a0, f0, f1); unp8(a1, f2, f3);
        float p = elu1(f0.x) + elu1(f0.y) + elu1(f0.z) + elu1(f0.w)
                + elu1(f1.x) + elu1(f1.y) + elu1(f1.z) + elu1(f1.w)
                + elu1(f2.x) + elu1(f2.y) + elu1(f2.z) + elu1(f2.w)
                + elu1(f3.x) + elu1(f3.y) + elu1(f3.z) + elu1(f3.w);
        p += __shfl_xor(p, 1, 64);
        p += __shfl_xor(p, 2, 64);
        if ((t & 3) == 0) rs[s] = p;
    }
    if (t < 64) zr[t] = zp[(size_t)seg * 64 + t];
    __syncthreads();

    // ---- scores: wave w computes rows [16w,16w+16) x all 64 cols
    const unsigned short* qrow = q + base + (size_t)(16 * w + lm) * 64;
    FragU aq0, aq1;
    aq0.u = *(const uint4*)(qrow + quad * 8);
    aq1.u = *(const uint4*)(qrow + 32 + quad * 8);
    floatx4 S[4];
    #pragma unroll
    for (int j = 0; j < 4; ++j) S[j] = (floatx4)(0.f);
    #pragma unroll
    for (int j = 0; j < 4; ++j) {
        const unsigned short* krow = k + base + (size_t)(j * 16 + lm) * 64;
        FragU b0, b1;
        b0.u = *(const uint4*)(krow + quad * 8);
        b1.u = *(const uint4*)(krow + 32 + quad * 8);
        S[j] = __builtin_amdgcn_mfma_f32_16x16x32_bf16(aq0.b, b0.b, S[j], 0, 0, 0);
        S[j] = __builtin_amdgcn_mfma_f32_16x16x32_bf16(aq1.b, b1.b, S[j], 0, 0, 0);
    }
    // ---- causal softmax in C-layout registers; write P bf16 to LDS
    const int srow0 = 16 * w + quad * 4;
    #pragma unroll
    for (int r = 0; r < 4; ++r) {
        const int s_g = srow0 + r;
        float m = -3.0e38f;
        #pragma unroll
        for (int j = 0; j < 4; ++j) {
            const int t_g = j * 16 + lm;
            const float val = (t_g <= s_g) ? S[j][r] * 0.125f : -3.0e38f;
            S[j][r] = val;
            m = fmaxf(m, val);
        }
        m = fmaxf(m, __shfl_xor(m, 1, 64));
        m = fmaxf(m, __shfl_xor(m, 2, 64));
        m = fmaxf(m, __shfl_xor(m, 4, 64));
        m = fmaxf(m, __shfl_xor(m, 8, 64));
        float ss = 0.f;
        #pragma unroll
        for (int j = 0; j < 4; ++j) {
            const int t_g = j * 16 + lm;
            const float e = (t_g <= s_g) ? __expf(S[j][r] - m) : 0.f;
            S[j][r] = e;
            ss += e;
        }
        ss += __shfl_xor(ss, 1, 64);
        ss += __shfl_xor(ss, 2, 64);
        ss += __shfl_xor(ss, 4, 64);
        ss += __shfl_xor(ss, 8, 64);
        const float inv = 1.f / ss;
        #pragma unroll
        for (int j = 0; j < 4; ++j)
            Pb[s_g * 72 + j * 16 + lm] = f2bf(S[j][r] * inv);
    }
    __syncthreads();

    // ---- A_dot = P@V and A_mem = sigma_q@mem (both C-layout accumulators)
    FragU ap0, ap1, as0, as1;
    ap0.u = *(const uint4*)&Pb[(16 * w + lm) * 72 + quad * 8];
    ap1.u = *(const uint4*)&Pb[(16 * w + lm) * 72 + 32 + quad * 8];
    {
        float4 f0, f1, f2, f3;
        unp8(aq0.u, f0, f1);
        unp8(aq1.u, f2, f3);
        f0.x = elu1(f0.x); f0.y = elu1(f0.y); f0.z = elu1(f0.z); f0.w = elu1(f0.w);
        f1.x = elu1(f1.x); f1.y = elu1(f1.y); f1.z = elu1(f1.z); f1.w = elu1(f1.w);
        f2.x = elu1(f2.x); f2.y = elu1(f2.y); f2.z = elu1(f2.z); f2.w = elu1(f2.w);
        f3.x = elu1(f3.x); f3.y = elu1(f3.y); f3.z = elu1(f3.z); f3.w = elu1(f3.w);
        as0.u = pack8bf(f0, f1);
        as1.u = pack8bf(f2, f3);
    }
    floatx4 AD[4], AM[4];
    #pragma unroll
    for (int j = 0; j < 4; ++j) { AD[j] = (floatx4)(0.f); AM[j] = (floatx4)(0.f); }
    #pragma unroll
    for (int j = 0; j < 4; ++j) {
        FragU bv0, bv1, bm0, bm1;
        bv0.u = *(const uint4*)&VT[(j * 16 + lm) * 72 + quad * 8];
        bv1.u = *(const uint4*)&VT[(j * 16 + lm) * 72 + 32 + quad * 8];
        bm0.u = *(const uint4*)&MT[(j * 16 + lm) * 72 + quad * 8];
        bm1.u = *(const uint4*)&MT[(j * 16 + lm) * 72 + 32 + quad * 8];
        AD[j] = __builtin_amdgcn_mfma_f32_16x16x32_bf16(ap0.b, bv0.b, AD[j], 0, 0, 0);
        AD[j] = __builtin_amdgcn_mfma_f32_16x16x32_bf16(ap1.b, bv1.b, AD[j], 0, 0, 0);
        AM[j] = __builtin_amdgcn_mfma_f32_16x16x32_bf16(as0.b, bm0.b, AM[j], 0, 0, 0);
        AM[j] = __builtin_amdgcn_mfma_f32_16x16x32_bf16(as1.b, bm1.b, AM[j], 0, 0, 0);
    }
    // ---- combine + store attn bf16
    #pragma unroll
    for (int j = 0; j < 4; ++j) {
        const int d = j * 16 + lm;
        const float zd = zr[d];
        #pragma unroll
        for (int r = 0; r < 4; ++r) {
            const int s_g = srow0 + r;
            const float den = rs[s_g] * zd + 1e-6f;
            const float o = gate * (AM[j][r] / den) + omg * AD[j][r];
            ab[base + (size_t)s_g * 64 + d] = f2bf(o);
        }
    }
}

extern "C" void kernel_launch(void* const* d_in, const int* in_sizes, int n_in,
                              void* d_out, int out_size, void* d_ws, size_t ws_size,
                              hipStream_t stream) {
    const float* x    = (const float*)d_in[0];
    const float* Wq   = (const float*)d_in[1];
    const float* bq   = (const float*)d_in[2];
    const float* Wk   = (const float*)d_in[3];
    const float* bk   = (const float*)d_in[4];
    const float* Wv   = (const float*)d_in[5];
    const float* bv   = (const float*)d_in[6];
    const float* Wo   = (const float*)d_in[7];
    const float* bo   = (const float*)d_in[8];
    const float* beta = (const float*)d_in[9];
    float* out = (float*)d_out;

    unsigned char* wsb = (unsigned char*)d_ws;
    unsigned short* xb  = (unsigned short*)(wsb);                       // 32 MB; reused as ab
    unsigned short* wb  = (unsigned short*)(wsb + (32ull << 20));       // 12 MB  [3072][2048]
    unsigned short* wob = (unsigned short*)(wsb + (44ull << 20));       // 2 MB   [1024][1024]
    unsigned short* qb  = (unsigned short*)(wsb + (46ull << 20));       // 16 MB
    unsigned short* kb  = (unsigned short*)(wsb + (62ull << 20));       // 16 MB
    unsigned short* vb  = (unsigned short*)(wsb + (78ull << 20));       // 16 MB
    float* Skv = (float*)(wsb + (94ull << 20));                         // 32 MB
    float* zc  = (float*)(wsb + (126ull << 20));                        // 0.5 MB
    unsigned short* ab = xb;   // attn bf16 (xb dead after gemm_qkv)

    cvt_bf16<<<8192, 256, 0, stream>>>(x, xb, 2097152);
    cvt_w<<<3584, 256, 0, stream>>>(Wq, Wk, Wv, Wo, wb, wob);

    gemm_qkv256<<<dim3(12, 64), 512, 0, stream>>>(xb, wb, bq, bk, bv, qb, kb, vb);
    seg_kv<<<2048, 256, 0, stream>>>(kb, vb, Skv, zc);
    prefix_mem<<<dim3(8, 128), 256, 0, stream>>>(Skv, zc);
    seg_attn<<<2048, 256, 0, stream>>>(qb, kb, vb, Skv, zc, beta, ab);
    gemm_out256<<<dim3(4, 64), 512, 0, stream>>>(ab, wob, bo, out);
}